// Round 1
// baseline (2203.791 us; speedup 1.0000x reference)
//
#include <hip/hip_runtime.h>
#include <math.h>

#define N_NODES 20000
#define T_STEPS 6
#define F_INCH  64
#define HC      256   // gat1: H*C
#define CH      64    // hidden width

// ---------------- CSR build ----------------
__global__ void k_count(const int* __restrict__ dst, int E, int* __restrict__ deg){
  int e = blockIdx.x*256 + threadIdx.x;
  if (e < E) atomicAdd(&deg[dst[e]], 1);
}

__global__ void k_scan(const int* __restrict__ deg, int* __restrict__ row_start, int N){
  __shared__ int lds[1024];
  int tid = threadIdx.x;
  int carry = 0;
  for (int base = 0; base < N; base += 1024){
    int v = (base + tid < N) ? deg[base + tid] : 0;
    lds[tid] = v;
    __syncthreads();
    for (int off = 1; off < 1024; off <<= 1){
      int t = (tid >= off) ? lds[tid - off] : 0;
      __syncthreads();
      lds[tid] += t;
      __syncthreads();
    }
    if (base + tid < N) row_start[base + tid] = carry + lds[tid] - v;  // exclusive
    int tot = lds[1023];
    __syncthreads();
    carry += tot;
  }
  if (tid == 0) row_start[N] = carry;
}

__global__ void k_scatter(const int* __restrict__ src, const int* __restrict__ dst, int E,
                          const int* __restrict__ row_start, int* __restrict__ cursor,
                          int* __restrict__ csr){
  int e = blockIdx.x*256 + threadIdx.x;
  if (e < E){
    int d = dst[e];
    int pos = atomicAdd(&cursor[d], 1);
    csr[row_start[d] + pos] = src[e];
  }
}

// sort each bucket (deg ~16) -> bitwise-deterministic CSR despite atomic scatter order
__global__ void k_sort(const int* __restrict__ row_start, int* __restrict__ csr, int N){
  int d = blockIdx.x*256 + threadIdx.x;
  if (d >= N) return;
  int s = row_start[d], e = row_start[d+1];
  for (int i = s+1; i < e; i++){
    int key = csr[i]; int j = i-1;
    while (j >= s && csr[j] > key){ csr[j+1] = csr[j]; j--; }
    csr[j+1] = key;
  }
}

// ---------------- GEMMs (fp32 vector; B matrices are tiny & cache-resident) ----------------
// C1 = A@B1, C2 = A@B2 ; A:[M,64] (row stride lda), B:[64,256], C:[M,256]
__global__ void k_gemm_dual_64_256(const float* __restrict__ A, int lda,
                                   const float* __restrict__ B1, const float* __restrict__ B2,
                                   float* __restrict__ C1, float* __restrict__ C2, int M){
  __shared__ float a_lds[4*64];
  int tid = threadIdx.x;
  int r0 = blockIdx.x*4;
  {
    int r = tid >> 6, k = tid & 63;
    int row = r0 + r;
    a_lds[tid] = (row < M) ? A[row*lda + k] : 0.f;
  }
  __syncthreads();
  float acc1[4] = {0,0,0,0}, acc2[4] = {0,0,0,0};
  #pragma unroll 8
  for (int k = 0; k < 64; k++){
    float b1 = B1[k*256 + tid], b2 = B2[k*256 + tid];
    #pragma unroll
    for (int r = 0; r < 4; r++){
      float a = a_lds[r*64 + k];
      acc1[r] = fmaf(a, b1, acc1[r]);
      acc2[r] = fmaf(a, b2, acc2[r]);
    }
  }
  #pragma unroll
  for (int r = 0; r < 4; r++){
    int row = r0 + r;
    if (row < M){ C1[row*256 + tid] = acc1[r]; C2[row*256 + tid] = acc2[r]; }
  }
}

// A:[M,256], B:[256,64], C:[M,64], dual outputs
__global__ void k_gemm_dual_256_64(const float* __restrict__ A,
                                   const float* __restrict__ B1, const float* __restrict__ B2,
                                   float* __restrict__ C1, float* __restrict__ C2, int M){
  __shared__ float a_lds[4*256];
  int tid = threadIdx.x;
  int r0 = blockIdx.x*4;
  for (int i = tid; i < 4*256; i += 256){
    int r = i >> 8, k = i & 255;
    int row = r0 + r;
    a_lds[i] = (row < M) ? A[row*256 + k] : 0.f;
  }
  __syncthreads();
  int r = tid >> 6, col = tid & 63;
  float acc1 = 0.f, acc2 = 0.f;
  #pragma unroll 8
  for (int k = 0; k < 256; k++){
    float b1 = B1[k*64 + col], b2 = B2[k*64 + col];
    float a = a_lds[r*256 + k];
    acc1 = fmaf(a, b1, acc1);
    acc2 = fmaf(a, b2, acc2);
  }
  int row = r0 + r;
  if (row < M){ C1[row*64 + col] = acc1; C2[row*64 + col] = acc2; }
}

// ---------------- GATv2 aggregation: one wave per (dst, head), online softmax ----------------
__device__ __forceinline__ float wave_sum(float v){
  #pragma unroll
  for (int off = 32; off; off >>= 1) v += __shfl_xor(v, off, 64);
  return v;
}

__global__ void k_gat1(const float* __restrict__ xl, const float* __restrict__ xr,
                       const int* __restrict__ row_start, const int* __restrict__ csr,
                       const float* __restrict__ att, const float* __restrict__ bias,
                       float* __restrict__ out){
  int dst = blockIdx.x;
  int h = threadIdx.x >> 6, lane = threadIdx.x & 63;
  int col = h*64 + lane;
  int s0 = row_start[dst], s1 = row_start[dst+1];
  float xrv  = xr[dst*HC + col];
  float attv = att[col];
  float m = -INFINITY, den = 0.f, acc = 0.f;
  for (int i = s0; i < s1; i++){
    int s = csr[i];
    float xlv = xl[s*HC + col];
    float t = xlv + xrv;
    t = t > 0.f ? t : 0.2f*t;                 // leaky_relu(0.2)
    float logit = wave_sum(t * attv);
    float mn = fmaxf(m, logit);
    float sc = __expf(m - mn);
    float w  = __expf(logit - mn);
    den = den*sc + w;
    acc = acc*sc + w*xlv;
    m = mn;
  }
  float r = (s1 > s0) ? acc/den : 0.f;
  r += bias[col];
  r = r > 0.f ? r : (__expf(r) - 1.f);        // elu
  out[dst*HC + col] = r;
}

__global__ void k_gat2(const float* __restrict__ xl, const float* __restrict__ xr,
                       const int* __restrict__ row_start, const int* __restrict__ csr,
                       const float* __restrict__ att, const float* __restrict__ bias,
                       float* __restrict__ out, int N){
  int wid = threadIdx.x >> 6, lane = threadIdx.x & 63;
  int dst = blockIdx.x*4 + wid;
  if (dst >= N) return;
  int s0 = row_start[dst], s1 = row_start[dst+1];
  float xrv  = xr[dst*CH + lane];
  float attv = att[lane];
  float m = -INFINITY, den = 0.f, acc = 0.f;
  for (int i = s0; i < s1; i++){
    int s = csr[i];
    float xlv = xl[s*CH + lane];
    float t = xlv + xrv;
    t = t > 0.f ? t : 0.2f*t;
    float logit = wave_sum(t * attv);
    float mn = fmaxf(m, logit);
    float sc = __expf(m - mn);
    float w  = __expf(logit - mn);
    den = den*sc + w;
    acc = acc*sc + w*xlv;
    m = mn;
  }
  float r = (s1 > s0) ? acc/den : 0.f;
  r += bias[lane];
  r = r > 0.f ? r : (__expf(r) - 1.f);
  out[dst*CH + lane] = r;
}

// ---------------- LSTM ----------------
__global__ void k_prep(const float* __restrict__ Wih, const float* __restrict__ Whh,
                       const float* __restrict__ bih, const float* __restrict__ bhh,
                       float* __restrict__ WihT, float* __restrict__ WhhT,
                       float* __restrict__ biasc){
  int tid = blockIdx.x*256 + threadIdx.x;
  if (tid < 64*256){
    int k = tid >> 8, j = tid & 255;
    WihT[k*256 + j] = Wih[j*64 + k];
    WhhT[k*256 + j] = Whh[j*64 + k];
  }
  if (tid < 256) biasc[tid] = bih[tid] + bhh[tid];
}

__global__ void k_lstm(const float* __restrict__ xt, const float* __restrict__ hin,
                       const float* __restrict__ cin,
                       const float* __restrict__ WihT, const float* __restrict__ WhhT,
                       const float* __restrict__ biasc,
                       float* __restrict__ hout, float* __restrict__ cout, int N){
  __shared__ float xs[4*64], hs[4*64];
  int tid = threadIdx.x;
  int r0 = blockIdx.x*4;
  {
    int r = tid >> 6, k = tid & 63;
    int row = r0 + r;
    xs[tid] = (row < N) ? xt[row*64 + k] : 0.f;
    hs[tid] = (row < N) ? hin[row*64 + k] : 0.f;
  }
  __syncthreads();
  int r = tid >> 6, u = tid & 63;
  float ai = biasc[u], af = biasc[64+u], ag = biasc[128+u], ao = biasc[192+u];
  #pragma unroll 4
  for (int k = 0; k < 64; k++){
    float xv = xs[r*64 + k], hv = hs[r*64 + k];
    const float* wi = &WihT[k*256];
    const float* wh = &WhhT[k*256];
    ai = fmaf(xv, wi[u],      ai); ai = fmaf(hv, wh[u],      ai);
    af = fmaf(xv, wi[64+u],   af); af = fmaf(hv, wh[64+u],   af);
    ag = fmaf(xv, wi[128+u],  ag); ag = fmaf(hv, wh[128+u],  ag);
    ao = fmaf(xv, wi[192+u],  ao); ao = fmaf(hv, wh[192+u],  ao);
  }
  int row = r0 + r;
  if (row < N){
    float cprev = cin[row*64 + u];
    float fi = 1.f/(1.f + __expf(-ai));
    float ff = 1.f/(1.f + __expf(-af));
    float fo = 1.f/(1.f + __expf(-ao));
    float gg = tanhf(ag);
    float c  = ff*cprev + fi*gg;
    float h  = fo*tanhf(c);
    cout[row*64 + u] = c;
    hout[row*64 + u] = h;
  }
}

// ---------------- MLP head (fused) ----------------
__global__ void k_mlp(const float* __restrict__ h, const float* __restrict__ Wfc1,
                      const float* __restrict__ bfc1, const float* __restrict__ Wout,
                      const float* __restrict__ bout, float* __restrict__ out, int N){
  int wid = threadIdx.x >> 6, lane = threadIdx.x & 63;
  int row = blockIdx.x*4 + wid;
  if (row >= N) return;
  int j = lane & 31;
  float acc = bfc1[j];
  const float* hr = &h[row*64];
  #pragma unroll 8
  for (int k = 0; k < 64; k++) acc = fmaf(hr[k], Wfc1[k*32 + j], acc);
  acc = fmaxf(acc, 0.f);
  float v = acc * Wout[j];
  #pragma unroll
  for (int off = 1; off < 32; off <<= 1) v += __shfl_xor(v, off, 64);
  if (lane == 0) out[row] = v + bout[0];
}

// ---------------- launch ----------------
extern "C" void kernel_launch(void* const* d_in, const int* in_sizes, int n_in,
                              void* d_out, int out_size, void* d_ws, size_t ws_size,
                              hipStream_t stream){
  const float* x    = (const float*)d_in[0];
  const int*   edge = (const int*)  d_in[1];
  const float* Wl1  = (const float*)d_in[2];
  const float* Wr1  = (const float*)d_in[3];
  const float* att1 = (const float*)d_in[4];
  const float* b1   = (const float*)d_in[5];
  const float* Wl2  = (const float*)d_in[6];
  const float* Wr2  = (const float*)d_in[7];
  const float* att2 = (const float*)d_in[8];
  const float* b2   = (const float*)d_in[9];
  const float* Wih  = (const float*)d_in[10];
  const float* Whh  = (const float*)d_in[11];
  const float* bih  = (const float*)d_in[12];
  const float* bhh  = (const float*)d_in[13];
  const float* Wfc1 = (const float*)d_in[14];
  const float* bfc1 = (const float*)d_in[15];
  const float* Wout = (const float*)d_in[16];
  const float* bout = (const float*)d_in[17];
  float* out = (float*)d_out;

  const int N = N_NODES;
  const int E = in_sizes[1] / 2;

  char* p = (char*)d_ws;
  auto alloc = [&](size_t bytes)->char*{ char* q = p; p += (bytes + 255) & ~(size_t)255; return q; };
  int* csr       = (int*)alloc((size_t)E*sizeof(int));
  int* row_start = (int*)alloc((size_t)(N+1)*sizeof(int));
  int* deg       = (int*)alloc((size_t)N*sizeof(int));
  int* cursor    = (int*)alloc((size_t)N*sizeof(int));
  float* xl1 = (float*)alloc((size_t)N*HC*4);
  float* xr1 = (float*)alloc((size_t)N*HC*4);
  float* h1  = (float*)alloc((size_t)N*HC*4);
  float* h2  = (float*)alloc((size_t)N*CH*4);
  float* ha  = (float*)alloc((size_t)N*CH*4);
  float* hb  = (float*)alloc((size_t)N*CH*4);
  float* ca  = (float*)alloc((size_t)N*CH*4);
  float* cb  = (float*)alloc((size_t)N*CH*4);
  float* WihT  = (float*)alloc(64*256*4);
  float* WhhT  = (float*)alloc(64*256*4);
  float* biasc = (float*)alloc(256*4);
  float* xl2 = xl1;   // reuse: xl1/xr1 are dead once h1 is computed
  float* xr2 = xr1;

  const int* srcIdx = edge;       // edge_index[0]
  const int* dstIdx = edge + E;   // edge_index[1]

  hipMemsetAsync(deg,    0, (size_t)N*4, stream);
  hipMemsetAsync(cursor, 0, (size_t)N*4, stream);
  hipMemsetAsync(ha, 0, (size_t)N*CH*4, stream);
  hipMemsetAsync(ca, 0, (size_t)N*CH*4, stream);

  k_count  <<<(E+255)/256, 256, 0, stream>>>(dstIdx, E, deg);
  k_scan   <<<1, 1024, 0, stream>>>(deg, row_start, N);
  k_scatter<<<(E+255)/256, 256, 0, stream>>>(srcIdx, dstIdx, E, row_start, cursor, csr);
  k_sort   <<<(N+255)/256, 256, 0, stream>>>(row_start, csr, N);
  k_prep   <<<64, 256, 0, stream>>>(Wih, Whh, bih, bhh, WihT, WhhT, biasc);

  float* hcur = ha; float* ccur = ca; float* hnxt = hb; float* cnxt = cb;
  for (int t = 0; t < T_STEPS; t++){
    k_gemm_dual_64_256<<<(N+3)/4, 256, 0, stream>>>(x + t*F_INCH, T_STEPS*F_INCH, Wl1, Wr1, xl1, xr1, N);
    k_gat1<<<N, 256, 0, stream>>>(xl1, xr1, row_start, csr, att1, b1, h1);
    k_gemm_dual_256_64<<<(N+3)/4, 256, 0, stream>>>(h1, Wl2, Wr2, xl2, xr2, N);
    k_gat2<<<(N+3)/4, 256, 0, stream>>>(xl2, xr2, row_start, csr, att2, b2, h2, N);
    k_lstm<<<(N+3)/4, 256, 0, stream>>>(h2, hcur, ccur, WihT, WhhT, biasc, hnxt, cnxt, N);
    float* th = hcur; hcur = hnxt; hnxt = th;
    float* tc = ccur; ccur = cnxt; cnxt = tc;
  }
  k_mlp<<<(N+3)/4, 256, 0, stream>>>(hcur, Wfc1, bfc1, Wout, bout, out, N);
}

// Round 2
// 1124.365 us; speedup vs baseline: 1.9600x; 1.9600x over previous
//
#include <hip/hip_runtime.h>
#include <math.h>

#define N_NODES 20000
#define T_STEPS 6
#define F_INCH  64
#define HC      256   // gat1: H*C
#define CH      64    // hidden width

__device__ __forceinline__ float fast_tanh(float x){
  float e = __expf(2.f*x);
  return 1.f - 2.f/(e + 1.f);
}

// ---------------- CSR build ----------------
__global__ void k_count(const int* __restrict__ dst, int E, int* __restrict__ deg){
  int e = blockIdx.x*256 + threadIdx.x;
  if (e < E) atomicAdd(&deg[dst[e]], 1);
}

__global__ void k_scan(const int* __restrict__ deg, int* __restrict__ row_start, int N){
  __shared__ int wsum[16];
  int tid = threadIdx.x, wid = tid >> 6, lane = tid & 63;
  int carry = 0;
  for (int base = 0; base < N; base += 1024){
    int v = (base + tid < N) ? deg[base + tid] : 0;
    int s = v;
    #pragma unroll
    for (int off = 1; off < 64; off <<= 1){
      int t = __shfl_up(s, off, 64);
      if (lane >= off) s += t;
    }
    if (lane == 63) wsum[wid] = s;
    __syncthreads();
    if (tid < 16){
      int w = wsum[tid];
      #pragma unroll
      for (int off = 1; off < 16; off <<= 1){
        int t = __shfl_up(w, off, 64);
        if (tid >= off) w += t;
      }
      wsum[tid] = w;
    }
    __syncthreads();
    int wpre = (wid == 0) ? 0 : wsum[wid-1];
    if (base + tid < N) row_start[base + tid] = carry + wpre + s - v;  // exclusive
    int tot = wsum[15];
    __syncthreads();
    carry += tot;
  }
  if (threadIdx.x == 0) row_start[N] = carry;
}

__global__ void k_scatter(const int* __restrict__ src, const int* __restrict__ dst, int E,
                          const int* __restrict__ row_start, int* __restrict__ cursor,
                          int* __restrict__ csr){
  int e = blockIdx.x*256 + threadIdx.x;
  if (e < E){
    int d = dst[e];
    int pos = atomicAdd(&cursor[d], 1);
    csr[row_start[d] + pos] = src[e];
  }
}

// sort each bucket (deg ~16) -> deterministic CSR despite atomic scatter order
__global__ void k_sort(const int* __restrict__ row_start, int* __restrict__ csr, int N){
  int d = blockIdx.x*256 + threadIdx.x;
  if (d >= N) return;
  int s = row_start[d], e = row_start[d+1];
  for (int i = s+1; i < e; i++){
    int key = csr[i]; int j = i-1;
    while (j >= s && csr[j] > key){ csr[j+1] = csr[j]; j--; }
    csr[j+1] = key;
  }
}

// ---------------- GEMM 64->256 dual, 16 rows/block ----------------
__global__ void k_gemm1(const float* __restrict__ A, int lda,
                        const float* __restrict__ B1, const float* __restrict__ B2,
                        float* __restrict__ C1, float* __restrict__ C2, int M){
  __shared__ float aT[64*20];   // aT[k*20 + r], pad 20 to spread write banks
  int tid = threadIdx.x;
  int r0 = blockIdx.x*16;
  for (int idx = tid; idx < 16*64; idx += 256){
    int r = idx >> 6, k = idx & 63;
    int row = r0 + r;
    aT[k*20 + r] = (row < M) ? A[(size_t)row*lda + k] : 0.f;
  }
  __syncthreads();
  float acc1[16], acc2[16];
  #pragma unroll
  for (int r = 0; r < 16; r++){ acc1[r] = 0.f; acc2[r] = 0.f; }
  const float4* aT4 = (const float4*)aT;
  #pragma unroll 4
  for (int k = 0; k < 64; k++){
    float b1 = B1[k*256 + tid];
    float b2 = B2[k*256 + tid];
    float4 a0 = aT4[k*5+0], a1 = aT4[k*5+1], a2 = aT4[k*5+2], a3 = aT4[k*5+3];
    float av[16] = {a0.x,a0.y,a0.z,a0.w, a1.x,a1.y,a1.z,a1.w,
                    a2.x,a2.y,a2.z,a2.w, a3.x,a3.y,a3.z,a3.w};
    #pragma unroll
    for (int r = 0; r < 16; r++){
      acc1[r] = fmaf(av[r], b1, acc1[r]);
      acc2[r] = fmaf(av[r], b2, acc2[r]);
    }
  }
  #pragma unroll
  for (int r = 0; r < 16; r++){
    int row = r0 + r;
    if (row < M){
      C1[(size_t)row*256 + tid] = acc1[r];
      C2[(size_t)row*256 + tid] = acc2[r];
    }
  }
}

// ---------------- GEMM 256->64 dual, 16 rows/block ----------------
__global__ void k_gemm2(const float* __restrict__ A,
                        const float* __restrict__ B1, const float* __restrict__ B2,
                        float* __restrict__ C1, float* __restrict__ C2, int M){
  __shared__ float aT[256*20];  // 20KB
  int tid = threadIdx.x;
  int r0 = blockIdx.x*16;
  for (int idx = tid; idx < 16*256; idx += 256){
    int r = idx >> 8, k = idx & 255;
    int row = r0 + r;
    aT[k*20 + r] = (row < M) ? A[(size_t)row*256 + k] : 0.f;
  }
  __syncthreads();
  int u = tid & 63, rq = tid >> 6;
  float acc1[4] = {0,0,0,0}, acc2[4] = {0,0,0,0};
  const float4* aT4 = (const float4*)aT;
  #pragma unroll 4
  for (int k = 0; k < 256; k++){
    float b1 = B1[k*64 + u];
    float b2 = B2[k*64 + u];
    float4 a = aT4[k*5 + rq];
    acc1[0] = fmaf(a.x, b1, acc1[0]); acc2[0] = fmaf(a.x, b2, acc2[0]);
    acc1[1] = fmaf(a.y, b1, acc1[1]); acc2[1] = fmaf(a.y, b2, acc2[1]);
    acc1[2] = fmaf(a.z, b1, acc1[2]); acc2[2] = fmaf(a.z, b2, acc2[2]);
    acc1[3] = fmaf(a.w, b1, acc1[3]); acc2[3] = fmaf(a.w, b2, acc2[3]);
  }
  #pragma unroll
  for (int j = 0; j < 4; j++){
    int row = r0 + rq*4 + j;
    if (row < M){
      C1[(size_t)row*64 + u] = acc1[j];
      C2[(size_t)row*64 + u] = acc2[j];
    }
  }
}

// ---------------- GATv2 layer 1: one wave per dst, float4/lane, online softmax ----------------
__global__ void k_gat1(const float* __restrict__ xl, const float* __restrict__ xr,
                       const int* __restrict__ row_start, const int* __restrict__ csr,
                       const float* __restrict__ att, const float* __restrict__ bias,
                       float* __restrict__ out, int N){
  int wid = threadIdx.x >> 6, lane = threadIdx.x & 63;
  int dst = blockIdx.x*4 + wid;
  if (dst >= N) return;
  const float4* xl4 = (const float4*)xl;
  float4 xr4 = ((const float4*)xr)[(size_t)dst*64 + lane];
  float4 at4 = ((const float4*)att)[lane];
  int s0 = row_start[dst], s1 = row_start[dst+1];
  float m = -INFINITY, den = 0.f, ax = 0.f, ay = 0.f, az = 0.f, aw = 0.f;
  if (s0 < s1){
    int s = csr[s0];
    float4 v = xl4[(size_t)s*64 + lane];
    for (int i = s0; i < s1; i++){
      float4 vn = v;
      if (i+1 < s1){
        int sn = csr[i+1];
        vn = xl4[(size_t)sn*64 + lane];
      }
      float tx = v.x + xr4.x; tx = fmaxf(tx, 0.2f*tx);
      float ty = v.y + xr4.y; ty = fmaxf(ty, 0.2f*ty);
      float tz = v.z + xr4.z; tz = fmaxf(tz, 0.2f*tz);
      float tw = v.w + xr4.w; tw = fmaxf(tw, 0.2f*tw);
      float p = fmaf(tx, at4.x, fmaf(ty, at4.y, fmaf(tz, at4.z, tw*at4.w)));
      // reduce within 16-lane head group
      p += __shfl_xor(p, 1, 64);
      p += __shfl_xor(p, 2, 64);
      p += __shfl_xor(p, 4, 64);
      p += __shfl_xor(p, 8, 64);
      float mn = fmaxf(m, p);
      float sc = __expf(m - mn);
      float w  = __expf(p - mn);
      den = fmaf(den, sc, w);
      ax = fmaf(ax, sc, w*v.x);
      ay = fmaf(ay, sc, w*v.y);
      az = fmaf(az, sc, w*v.z);
      aw = fmaf(aw, sc, w*v.w);
      m = mn;
      v = vn;
    }
  }
  float invd = (s1 > s0) ? 1.f/den : 0.f;
  float4 b4 = ((const float4*)bias)[lane];
  float rx = fmaf(ax, invd, b4.x);
  float ry = fmaf(ay, invd, b4.y);
  float rz = fmaf(az, invd, b4.z);
  float rw = fmaf(aw, invd, b4.w);
  rx = rx > 0.f ? rx : (__expf(rx) - 1.f);
  ry = ry > 0.f ? ry : (__expf(ry) - 1.f);
  rz = rz > 0.f ? rz : (__expf(rz) - 1.f);
  rw = rw > 0.f ? rw : (__expf(rw) - 1.f);
  ((float4*)out)[(size_t)dst*64 + lane] = make_float4(rx, ry, rz, rw);
}

// ---------------- GATv2 layer 2: one wave per dst, 4 edges in flight ----------------
__global__ void k_gat2(const float* __restrict__ xl, const float* __restrict__ xr,
                       const int* __restrict__ row_start, const int* __restrict__ csr,
                       const float* __restrict__ att, const float* __restrict__ bias,
                       float* __restrict__ out, int N){
  int wid = threadIdx.x >> 6, lane = threadIdx.x & 63;
  int dst = blockIdx.x*4 + wid;
  if (dst >= N) return;
  int g = lane >> 4, q = lane & 15;          // edge slot, channel quad
  const float4* xl4 = (const float4*)xl;
  float4 xr4 = ((const float4*)xr)[(size_t)dst*16 + q];
  float4 at4 = ((const float4*)att)[q];
  int s0 = row_start[dst], s1 = row_start[dst+1];
  float m = -INFINITY, den = 0.f, ax = 0.f, ay = 0.f, az = 0.f, aw = 0.f;
  int i = s0 + g;
  if (i < s1){
    int s = csr[i];
    float4 v = xl4[(size_t)s*16 + q];
    for (; i < s1; i += 4){
      float4 vn = v;
      if (i+4 < s1){
        int sn = csr[i+4];
        vn = xl4[(size_t)sn*16 + q];
      }
      float tx = v.x + xr4.x; tx = fmaxf(tx, 0.2f*tx);
      float ty = v.y + xr4.y; ty = fmaxf(ty, 0.2f*ty);
      float tz = v.z + xr4.z; tz = fmaxf(tz, 0.2f*tz);
      float tw = v.w + xr4.w; tw = fmaxf(tw, 0.2f*tw);
      float p = fmaf(tx, at4.x, fmaf(ty, at4.y, fmaf(tz, at4.z, tw*at4.w)));
      p += __shfl_xor(p, 1, 64);
      p += __shfl_xor(p, 2, 64);
      p += __shfl_xor(p, 4, 64);
      p += __shfl_xor(p, 8, 64);
      float mn = fmaxf(m, p);
      float sc = __expf(m - mn);
      float w  = __expf(p - mn);
      den = fmaf(den, sc, w);
      ax = fmaf(ax, sc, w*v.x);
      ay = fmaf(ay, sc, w*v.y);
      az = fmaf(az, sc, w*v.z);
      aw = fmaf(aw, sc, w*v.w);
      m = mn;
      v = vn;
    }
  }
  // merge the 4 edge groups
  float M2 = fmaxf(m, __shfl_xor(m, 16, 64));
  float Mx = fmaxf(M2, __shfl_xor(M2, 32, 64));
  float sc = (m > -INFINITY) ? __expf(m - Mx) : 0.f;
  den *= sc; ax *= sc; ay *= sc; az *= sc; aw *= sc;
  den += __shfl_xor(den, 16, 64); den += __shfl_xor(den, 32, 64);
  ax  += __shfl_xor(ax, 16, 64);  ax  += __shfl_xor(ax, 32, 64);
  ay  += __shfl_xor(ay, 16, 64);  ay  += __shfl_xor(ay, 32, 64);
  az  += __shfl_xor(az, 16, 64);  az  += __shfl_xor(az, 32, 64);
  aw  += __shfl_xor(aw, 16, 64);  aw  += __shfl_xor(aw, 32, 64);
  float invd = (s1 > s0) ? 1.f/den : 0.f;
  float4 b4 = ((const float4*)bias)[q];
  float rx = fmaf(ax, invd, b4.x);
  float ry = fmaf(ay, invd, b4.y);
  float rz = fmaf(az, invd, b4.z);
  float rw = fmaf(aw, invd, b4.w);
  rx = rx > 0.f ? rx : (__expf(rx) - 1.f);
  ry = ry > 0.f ? ry : (__expf(ry) - 1.f);
  rz = rz > 0.f ? rz : (__expf(rz) - 1.f);
  rw = rw > 0.f ? rw : (__expf(rw) - 1.f);
  if (g == 0) ((float4*)out)[(size_t)dst*16 + q] = make_float4(rx, ry, rz, rw);
}

// ---------------- LSTM prep ----------------
__global__ void k_prep(const float* __restrict__ Wih, const float* __restrict__ Whh,
                       const float* __restrict__ bih, const float* __restrict__ bhh,
                       float* __restrict__ WihT, float* __restrict__ WhhT,
                       float* __restrict__ biasc){
  int tid = blockIdx.x*256 + threadIdx.x;
  if (tid < 64*256){
    int k = tid >> 8, j = tid & 255;
    WihT[k*256 + j] = Wih[j*64 + k];
    WhhT[k*256 + j] = Whh[j*64 + k];
  }
  if (tid < 256) biasc[tid] = bih[tid] + bhh[tid];
}

// ---------------- LSTM step, 16 rows/block ----------------
__global__ void k_lstm(const float* __restrict__ xt, const float* __restrict__ hin,
                       const float* __restrict__ cin,
                       const float* __restrict__ WihT, const float* __restrict__ WhhT,
                       const float* __restrict__ biasc,
                       float* __restrict__ hout, float* __restrict__ cout, int N){
  __shared__ float xT[64*20], hT[64*20];
  int tid = threadIdx.x;
  int r0 = blockIdx.x*16;
  for (int idx = tid; idx < 16*64; idx += 256){
    int r = idx >> 6, k = idx & 63;
    int row = r0 + r;
    xT[k*20 + r] = (row < N) ? xt[(size_t)row*64 + k] : 0.f;
    hT[k*20 + r] = (row < N) ? hin[(size_t)row*64 + k] : 0.f;
  }
  __syncthreads();
  int u = tid & 63, rq = tid >> 6;
  float bi = biasc[u], bf = biasc[64+u], bg = biasc[128+u], bo = biasc[192+u];
  float ai[4], af[4], ag[4], ao[4];
  #pragma unroll
  for (int j = 0; j < 4; j++){ ai[j]=bi; af[j]=bf; ag[j]=bg; ao[j]=bo; }
  const float4* xT4 = (const float4*)xT;
  const float4* hT4 = (const float4*)hT;
  #pragma unroll 2
  for (int k = 0; k < 64; k++){
    float4 xv4 = xT4[k*5 + rq];
    float4 hv4 = hT4[k*5 + rq];
    const float* wi = &WihT[k*256];
    const float* wh = &WhhT[k*256];
    float wii = wi[u], wif = wi[64+u], wig = wi[128+u], wio = wi[192+u];
    float whi = wh[u], whf = wh[64+u], whg = wh[128+u], who = wh[192+u];
    float xv[4] = {xv4.x, xv4.y, xv4.z, xv4.w};
    float hv[4] = {hv4.x, hv4.y, hv4.z, hv4.w};
    #pragma unroll
    for (int j = 0; j < 4; j++){
      ai[j] = fmaf(xv[j], wii, ai[j]); ai[j] = fmaf(hv[j], whi, ai[j]);
      af[j] = fmaf(xv[j], wif, af[j]); af[j] = fmaf(hv[j], whf, af[j]);
      ag[j] = fmaf(xv[j], wig, ag[j]); ag[j] = fmaf(hv[j], whg, ag[j]);
      ao[j] = fmaf(xv[j], wio, ao[j]); ao[j] = fmaf(hv[j], who, ao[j]);
    }
  }
  #pragma unroll
  for (int j = 0; j < 4; j++){
    int row = r0 + rq*4 + j;
    if (row < N){
      float cprev = cin[(size_t)row*64 + u];
      float I = 1.f/(1.f + __expf(-ai[j]));
      float F = 1.f/(1.f + __expf(-af[j]));
      float O = 1.f/(1.f + __expf(-ao[j]));
      float G = fast_tanh(ag[j]);
      float c = fmaf(F, cprev, I*G);
      float h = O * fast_tanh(c);
      cout[(size_t)row*64 + u] = c;
      hout[(size_t)row*64 + u] = h;
    }
  }
}

// ---------------- MLP head (fused) ----------------
__global__ void k_mlp(const float* __restrict__ h, const float* __restrict__ Wfc1,
                      const float* __restrict__ bfc1, const float* __restrict__ Wout,
                      const float* __restrict__ bout, float* __restrict__ out, int N){
  int wid = threadIdx.x >> 6, lane = threadIdx.x & 63;
  int row = blockIdx.x*4 + wid;
  if (row >= N) return;
  int j = lane & 31;
  float acc = bfc1[j];
  const float* hr = &h[(size_t)row*64];
  #pragma unroll 8
  for (int k = 0; k < 64; k++) acc = fmaf(hr[k], Wfc1[k*32 + j], acc);
  acc = fmaxf(acc, 0.f);
  float v = acc * Wout[j];
  #pragma unroll
  for (int off = 1; off < 32; off <<= 1) v += __shfl_xor(v, off, 64);
  if (lane == 0) out[row] = v + bout[0];
}

// ---------------- launch ----------------
extern "C" void kernel_launch(void* const* d_in, const int* in_sizes, int n_in,
                              void* d_out, int out_size, void* d_ws, size_t ws_size,
                              hipStream_t stream){
  const float* x    = (const float*)d_in[0];
  const int*   edge = (const int*)  d_in[1];
  const float* Wl1  = (const float*)d_in[2];
  const float* Wr1  = (const float*)d_in[3];
  const float* att1 = (const float*)d_in[4];
  const float* b1   = (const float*)d_in[5];
  const float* Wl2  = (const float*)d_in[6];
  const float* Wr2  = (const float*)d_in[7];
  const float* att2 = (const float*)d_in[8];
  const float* b2   = (const float*)d_in[9];
  const float* Wih  = (const float*)d_in[10];
  const float* Whh  = (const float*)d_in[11];
  const float* bih  = (const float*)d_in[12];
  const float* bhh  = (const float*)d_in[13];
  const float* Wfc1 = (const float*)d_in[14];
  const float* bfc1 = (const float*)d_in[15];
  const float* Wout = (const float*)d_in[16];
  const float* bout = (const float*)d_in[17];
  float* out = (float*)d_out;

  const int N = N_NODES;
  const int E = in_sizes[1] / 2;

  char* p = (char*)d_ws;
  auto alloc = [&](size_t bytes)->char*{ char* q = p; p += (bytes + 255) & ~(size_t)255; return q; };
  int* csr       = (int*)alloc((size_t)E*sizeof(int));
  int* row_start = (int*)alloc((size_t)(N+1)*sizeof(int));
  int* deg       = (int*)alloc((size_t)N*sizeof(int));
  int* cursor    = (int*)alloc((size_t)N*sizeof(int));
  float* xl1 = (float*)alloc((size_t)N*HC*4);
  float* xr1 = (float*)alloc((size_t)N*HC*4);
  float* h1  = (float*)alloc((size_t)N*HC*4);
  float* h2  = (float*)alloc((size_t)N*CH*4);
  float* ha  = (float*)alloc((size_t)N*CH*4);
  float* hb  = (float*)alloc((size_t)N*CH*4);
  float* ca  = (float*)alloc((size_t)N*CH*4);
  float* cb  = (float*)alloc((size_t)N*CH*4);
  float* WihT  = (float*)alloc(64*256*4);
  float* WhhT  = (float*)alloc(64*256*4);
  float* biasc = (float*)alloc(256*4);
  float* xl2 = xl1;   // reuse: xl1/xr1 dead once h1 is computed
  float* xr2 = xr1;

  const int* srcIdx = edge;       // edge_index[0]
  const int* dstIdx = edge + E;   // edge_index[1]

  hipMemsetAsync(deg,    0, (size_t)N*4, stream);
  hipMemsetAsync(cursor, 0, (size_t)N*4, stream);
  hipMemsetAsync(ha, 0, (size_t)N*CH*4, stream);
  hipMemsetAsync(ca, 0, (size_t)N*CH*4, stream);

  k_count  <<<(E+255)/256, 256, 0, stream>>>(dstIdx, E, deg);
  k_scan   <<<1, 1024, 0, stream>>>(deg, row_start, N);
  k_scatter<<<(E+255)/256, 256, 0, stream>>>(srcIdx, dstIdx, E, row_start, cursor, csr);
  k_sort   <<<(N+255)/256, 256, 0, stream>>>(row_start, csr, N);
  k_prep   <<<64, 256, 0, stream>>>(Wih, Whh, bih, bhh, WihT, WhhT, biasc);

  float* hcur = ha; float* ccur = ca; float* hnxt = hb; float* cnxt = cb;
  for (int t = 0; t < T_STEPS; t++){
    k_gemm1<<<(N+15)/16, 256, 0, stream>>>(x + t*F_INCH, T_STEPS*F_INCH, Wl1, Wr1, xl1, xr1, N);
    k_gat1 <<<(N+3)/4,   256, 0, stream>>>(xl1, xr1, row_start, csr, att1, b1, h1, N);
    k_gemm2<<<(N+15)/16, 256, 0, stream>>>(h1, Wl2, Wr2, xl2, xr2, N);
    k_gat2 <<<(N+3)/4,   256, 0, stream>>>(xl2, xr2, row_start, csr, att2, b2, h2, N);
    k_lstm <<<(N+15)/16, 256, 0, stream>>>(h2, hcur, ccur, WihT, WhhT, biasc, hnxt, cnxt, N);
    float* th = hcur; hcur = hnxt; hnxt = th;
    float* tc = ccur; ccur = cnxt; cnxt = tc;
  }
  k_mlp<<<(N+3)/4, 256, 0, stream>>>(hcur, Wfc1, bfc1, Wout, bout, out, N);
}